// Round 2
// baseline (831.574 us; speedup 1.0000x reference)
//
#include <hip/hip_runtime.h>
#include <hip/hip_bf16.h>
#include <stdint.h>

#define B_ 16
#define S_ 2048
#define D_ 1024
#define H_ 4096
#define E_ 4
#define C_ 1000
#define NTOK (B_*S_)

typedef __attribute__((ext_vector_type(8))) short short8;
typedef __attribute__((ext_vector_type(4))) float f32x4;

__device__ __forceinline__ unsigned short f2bf(float f){
  unsigned u = __float_as_uint(f);
  u += 0x7fffu + ((u>>16)&1u);
  return (unsigned short)(u>>16);
}

__device__ __forceinline__ void gload16(const void* g, void* l){
  __builtin_amdgcn_global_load_lds(
    (const __attribute__((address_space(1))) unsigned*)(uintptr_t)g,
    (__attribute__((address_space(3))) unsigned*)(uintptr_t)l, 16, 0, 0);
}

// ---------------- K0: W1 [E][D][H] fp32 -> W1T [E][H][D] bf16 ----------------
__global__ __launch_bounds__(256) void k0_transpose(const float* __restrict__ W1,
                                                    unsigned short* __restrict__ w1t){
  __shared__ float t[32][33];
  int tx = threadIdx.x, ty = threadIdx.y;
  int h0 = blockIdx.x*32, d0 = blockIdx.y*32, e = blockIdx.z;
  const float* src = W1 + ((size_t)e*D_ + d0)*H_ + h0;
#pragma unroll
  for (int i=0;i<4;i++) t[ty+8*i][tx] = src[(size_t)(ty+8*i)*H_ + tx];
  __syncthreads();
  unsigned short* dst = w1t + ((size_t)e*H_ + h0)*D_ + d0;
#pragma unroll
  for (int i=0;i<4;i++) dst[(size_t)(ty+8*i)*D_ + tx] = f2bf(t[tx][ty+8*i]);
}

// ---------------- K1: gating (fp32) + x->bf16 cast ----------------
__global__ __launch_bounds__(256) void k1_gate(const float* __restrict__ x,
    const float* __restrict__ Wg, const float* __restrict__ bg,
    unsigned short* __restrict__ xbf, float* __restrict__ gate,
    int* __restrict__ eidx, float* __restrict__ probSum,
    unsigned* __restrict__ cntBE, float* __restrict__ gateSum){
  __shared__ float ps_l[4];
  __shared__ float gs_l[64];
  __shared__ unsigned cnt_l[64];
  int tid = threadIdx.x, lane = tid&63, wid = tid>>6;
  if (tid<4) ps_l[tid]=0.f;
  if (tid<64){ gs_l[tid]=0.f; cnt_l[tid]=0u; }
  __syncthreads();
  const float4* wg4 = (const float4*)Wg;   // wg4[d] = Wg[d][0..3]
  float4 wr[16];
#pragma unroll
  for (int k=0;k<4;k++)
#pragma unroll
    for (int c=0;c<4;c++) wr[k*4+c] = wg4[(lane + 64*k)*4 + c];
  float bgv0=bg[0], bgv1=bg[1], bgv2=bg[2], bgv3=bg[3];
  for (int it=0; it<16; ++it){
    int t = it*2048 + blockIdx.x*4 + wid;
    const float4* xr = (const float4*)(x + (size_t)t*D_);
    ushort4* xo = (ushort4*)(xbf + (size_t)t*D_);
    float4 acc = make_float4(0.f,0.f,0.f,0.f);
#pragma unroll
    for (int k=0;k<4;k++){
      float4 xv = xr[lane + 64*k];
      float4 w;
      w = wr[k*4+0]; acc.x += xv.x*w.x; acc.y += xv.x*w.y; acc.z += xv.x*w.z; acc.w += xv.x*w.w;
      w = wr[k*4+1]; acc.x += xv.y*w.x; acc.y += xv.y*w.y; acc.z += xv.y*w.z; acc.w += xv.y*w.w;
      w = wr[k*4+2]; acc.x += xv.z*w.x; acc.y += xv.z*w.y; acc.z += xv.z*w.z; acc.w += xv.z*w.w;
      w = wr[k*4+3]; acc.x += xv.w*w.x; acc.y += xv.w*w.y; acc.z += xv.w*w.z; acc.w += xv.w*w.w;
      ushort4 o; o.x=f2bf(xv.x); o.y=f2bf(xv.y); o.z=f2bf(xv.z); o.w=f2bf(xv.w);
      xo[lane + 64*k] = o;
    }
#pragma unroll
    for (int mk=32; mk; mk>>=1){
      acc.x += __shfl_xor(acc.x, mk);
      acc.y += __shfl_xor(acc.y, mk);
      acc.z += __shfl_xor(acc.z, mk);
      acc.w += __shfl_xor(acc.w, mk);
    }
    if (lane==0){
      float l0=acc.x+bgv0, l1=acc.y+bgv1, l2=acc.z+bgv2, l3=acc.w+bgv3;
      int idx=0; float mv=l0;
      if (l1>mv){mv=l1;idx=1;}
      if (l2>mv){mv=l2;idx=2;}
      if (l3>mv){mv=l3;idx=3;}
      float e0=__expf(l0-mv), e1=__expf(l1-mv), e2=__expf(l2-mv), e3=__expf(l3-mv);
      float inv = 1.0f/(e0+e1+e2+e3);
      float gv = inv;                       // exp(0)*inv = top-1 prob
      eidx[t]=idx; gate[t]=gv;
      atomicAdd(&ps_l[0], e0*inv); atomicAdd(&ps_l[1], e1*inv);
      atomicAdd(&ps_l[2], e2*inv); atomicAdd(&ps_l[3], e3*inv);
      int bb = t >> 11;                     // S=2048
      atomicAdd(&cnt_l[idx*16+bb], 1u);
      atomicAdd(&gs_l[idx*16+bb], gv);
    }
  }
  __syncthreads();
  if (tid<4) atomicAdd(&probSum[tid], ps_l[tid]);
  if (tid<64){ atomicAdd(&cntBE[tid], cnt_l[tid]); atomicAdd(&gateSum[tid], gs_l[tid]); }
}

// ---------------- K2a: offsets + aux loss ----------------
__global__ __launch_bounds__(64) void k2a_offsets(const unsigned* __restrict__ cntBE,
    const float* __restrict__ probSum, unsigned* __restrict__ groupOff,
    unsigned* __restrict__ cursor, float* __restrict__ out_aux){
  if (threadIdx.x==0){
    unsigned off=0;
    for (int g=0; g<64; ++g){ groupOff[g]=off; cursor[g*32]=off; off += cntBE[g]; }
    groupOff[64]=off;
    float aux=0.f;
    for (int e=0;e<4;e++){
      float ce=0.f;
      for (int b=0;b<16;b++) ce += (float)cntBE[e*16+b];
      aux += ce * probSum[e];
    }
    aux *= 4.0f/(32768.0f*32768.0f);
    *out_aux = aux;
  }
}

// ---------------- K2b: counting-sort scatter ----------------
__global__ __launch_bounds__(256) void k2b_scatter(const int* __restrict__ eidx,
   unsigned* __restrict__ cursor, int* __restrict__ perm){
  int t = blockIdx.x*256 + threadIdx.x;
  int e = eidx[t]; int bb = t>>11; int g = e*16+bb;
  unsigned pos = atomicAdd(&cursor[g*32], 1u);
  perm[pos] = (int)t;
}

// ---------------- K3: grouped up-GEMM (bf16 MFMA) + fused relu/gate/z-reduce --
__global__ __launch_bounds__(256) void k3_moe(const unsigned short* __restrict__ xbf,
    const unsigned short* __restrict__ w1t, const float* __restrict__ b1,
    const float* __restrict__ gate, const int* __restrict__ perm,
    const unsigned* __restrict__ groupOff, float* __restrict__ z){
  __shared__ unsigned short xs[128*64];   // 16 KB, row-major, chunk-swizzled
  __shared__ unsigned short wt[128*64];   // 16 KB, W1T cols as rows
  __shared__ int   prm_s[128];
  __shared__ float gls[128];
  int tid = threadIdx.x, lane = tid&63, w = tid>>6;
  int g = blockIdx.y;
  int e = g>>4;
  int col0 = blockIdx.x*128;
  int r0 = (int)groupOff[g];
  int cnt = (int)groupOff[g+1] - r0;
  if (cnt<=0) return;
  int m = lane&15, p = lane>>4, sw = m&7;
  int rbase = (w>>1)*64, cbase = (w&1)*64;
  float b1v[4];
#pragma unroll
  for (int cf=0;cf<4;cf++) b1v[cf] = b1[e*H_ + col0 + cbase + cf*16 + m];
  float zacc[4] = {0.f,0.f,0.f,0.f};
  int nchunk = (cnt+127)>>7;
  for (int ch=0; ch<nchunk; ++ch){
    __syncthreads();
    if (tid<128){
      int ri = ch*128 + tid;
      int rid = r0 + (ri < cnt ? ri : cnt-1);
      int pm = perm[rid];
      prm_s[tid] = pm;
      gls[tid] = (ri<cnt) ? gate[pm] : 0.f;
    }
    __syncthreads();
    f32x4 acc[4][4];
    f32x4 vz = {0.f,0.f,0.f,0.f};
#pragma unroll
    for (int a=0;a<4;a++)
#pragma unroll
      for (int c2=0;c2<4;c2++) acc[a][c2] = vz;
    for (int kt=0; kt<16; ++kt){
#pragma unroll
      for (int q=0;q<4;q++){            // stage x rows (gather via perm)
        int cidx = (q*4+w)*64 + lane;
        int row = cidx>>3, ci = cidx&7;
        const unsigned short* src = xbf + (size_t)prm_s[row]*D_ + kt*64 + ((ci ^ (row&7))<<3);
        gload16(src, (char*)xs + (q*4+w)*1024);
      }
#pragma unroll
      for (int q=0;q<4;q++){            // stage W1T col-rows
        int cidx = (q*4+w)*64 + lane;
        int col = cidx>>3, ci = cidx&7;
        const unsigned short* src = w1t + ((size_t)(e*H_ + col0 + col))*D_ + kt*64 + ((ci ^ (col&7))<<3);
        gload16(src, (char*)wt + (q*4+w)*1024);
      }
      __syncthreads();
#pragma unroll
      for (int kk=0;kk<2;kk++){
        short8 af[4], bfr[4];
#pragma unroll
        for (int rf=0;rf<4;rf++)
          af[rf] = *(const short8*)&xs[(rbase+rf*16+m)*64 + (((kk*4+p)^sw)<<3)];
#pragma unroll
        for (int cf=0;cf<4;cf++)
          bfr[cf] = *(const short8*)&wt[(cbase+cf*16+m)*64 + (((kk*4+p)^sw)<<3)];
#pragma unroll
        for (int rf=0;rf<4;rf++)
#pragma unroll
          for (int cf=0;cf<4;cf++)
            acc[rf][cf] = __builtin_amdgcn_mfma_f32_16x16x32_bf16(af[rf], bfr[cf], acc[rf][cf], 0,0,0);
      }
      __syncthreads();
    }
    // epilogue: relu(h+b1)*gate, reduce over rows into zacc (C layout: col=lane&15, row=p*4+j)
#pragma unroll
    for (int rf=0;rf<4;rf++){
      int rb = rbase + rf*16 + p*4;
      float g0=gls[rb+0], g1=gls[rb+1], g2=gls[rb+2], g3=gls[rb+3];
#pragma unroll
      for (int cf=0;cf<4;cf++){
        f32x4 a = acc[rf][cf];
        zacc[cf] += g0*fmaxf(a[0]+b1v[cf],0.f) + g1*fmaxf(a[1]+b1v[cf],0.f)
                  + g2*fmaxf(a[2]+b1v[cf],0.f) + g3*fmaxf(a[3]+b1v[cf],0.f);
      }
    }
  }
#pragma unroll
  for (int cf=0;cf<4;cf++){
    float v = zacc[cf];
    v += __shfl_xor(v, 16);
    v += __shfl_xor(v, 32);
    if (p==0) atomicAdd(&z[(size_t)g*H_ + col0 + cbase + cf*16 + m], v);
  }
}

// ---------------- K4a: pooled += z @ W2 (fp32, memory-bound) ----------------
__global__ __launch_bounds__(256) void k4a_down(const float* __restrict__ z,
    const float* __restrict__ W2, float* __restrict__ pooled){
  __shared__ float zs[16*256];
  int tid = threadIdx.x;
  int d0 = blockIdx.x*256, j0 = blockIdx.y*256, e = blockIdx.z;
  for (int idx=tid; idx<4096; idx+=256){
    int bb = idx>>8, j = idx&255;
    zs[idx] = z[((size_t)(e*16+bb))*H_ + j0 + j];
  }
  __syncthreads();
  float acc[16];
#pragma unroll
  for (int bb=0;bb<16;bb++) acc[bb]=0.f;
  const float* w2b = W2 + ((size_t)e*H_ + j0)*D_ + d0 + tid;
  for (int j4=0; j4<256; j4+=4){
    float w0 = w2b[(size_t)(j4+0)*D_];
    float w1v= w2b[(size_t)(j4+1)*D_];
    float w2v= w2b[(size_t)(j4+2)*D_];
    float w3v= w2b[(size_t)(j4+3)*D_];
#pragma unroll
    for (int bb=0;bb<16;bb++){
      float4 zv = *(const float4*)&zs[bb*256 + j4];
      acc[bb] += zv.x*w0 + zv.y*w1v + zv.z*w2v + zv.w*w3v;
    }
  }
#pragma unroll
  for (int bb=0;bb<16;bb++) atomicAdd(&pooled[bb*D_ + d0 + tid], acc[bb]);
}

// ---------------- K4b: +bias term, /S, head GEMV ----------------
__global__ __launch_bounds__(256) void k4b_head(const float* __restrict__ pooled,
    const float* __restrict__ gateSum, const float* __restrict__ b2,
    const float* __restrict__ Wh, const float* __restrict__ bh,
    float* __restrict__ out){
  __shared__ float plf[1024];
  int tid = threadIdx.x;
  int bb = blockIdx.y, cc = blockIdx.x;
  float gs0 = gateSum[0*16+bb], gs1 = gateSum[1*16+bb];
  float gs2 = gateSum[2*16+bb], gs3 = gateSum[3*16+bb];
  for (int d=tid; d<1024; d+=256){
    float pv = pooled[bb*D_ + d];
    pv += gs0*b2[0*D_+d] + gs1*b2[1*D_+d] + gs2*b2[2*D_+d] + gs3*b2[3*D_+d];
    plf[d] = pv * (1.0f/2048.0f);
  }
  __syncthreads();
  int c = cc*256 + tid;
  if (c < C_){
    float acc = bh[c];
#pragma unroll 4
    for (int d=0; d<1024; ++d) acc += plf[d]*Wh[(size_t)d*C_ + c];
    out[bb*C_ + c] = acc;
  }
}

extern "C" void kernel_launch(void* const* d_in, const int* in_sizes, int n_in,
                              void* d_out, int out_size, void* d_ws, size_t ws_size,
                              hipStream_t stream){
  (void)in_sizes; (void)n_in; (void)out_size; (void)ws_size;
  const float* x  = (const float*)d_in[0];
  const float* Wg = (const float*)d_in[1];
  const float* bg = (const float*)d_in[2];
  const float* W1 = (const float*)d_in[3];
  const float* b1 = (const float*)d_in[4];
  const float* W2 = (const float*)d_in[5];
  const float* b2 = (const float*)d_in[6];
  const float* Wh = (const float*)d_in[7];
  const float* bh = (const float*)d_in[8];
  float* out = (float*)d_out;
  char* ws = (char*)d_ws;

  float*    probSum = (float*)(ws + 0);        // 4
  unsigned* cntBE   = (unsigned*)(ws + 64);    // 64  (g = e*16+b)
  float*    gateSum = (float*)(ws + 320);      // 64
  unsigned* groupOff= (unsigned*)(ws + 576);   // 65
  unsigned* cursor  = (unsigned*)(ws + 1024);  // 64, stride 32 (cacheline pad)
  float*    z       = (float*)(ws + 16384);    // 64*4096 fp32 = 1 MB
  float*    pooled  = (float*)(ws + 1064960);  // 16*1024 fp32
  unsigned short* xbf = (unsigned short*)(ws + 2097152);    // 67 MB bf16
  int*      perm    = (int*)(ws + 69206016);   // 32768
  float*    gate    = (float*)(ws + 69337088); // 32768
  int*      eidx    = (int*)(ws + 69468160);   // 32768
  unsigned short* w1t = (unsigned short*)(ws + 69599232);   // 33.5 MB bf16

  hipMemsetAsync(ws, 0, 1130496, stream);   // zero accumulators + z + pooled
  k0_transpose<<<dim3(128,32,4), dim3(32,8), 0, stream>>>(W1, w1t);
  k1_gate<<<512, 256, 0, stream>>>(x, Wg, bg, xbf, gate, eidx, probSum, cntBE, gateSum);
  k2a_offsets<<<1, 64, 0, stream>>>(cntBE, probSum, groupOff, cursor, out + 16000);
  k2b_scatter<<<128, 256, 0, stream>>>(eidx, cursor, perm);
  k3_moe<<<dim3(32,64), 256, 0, stream>>>(xbf, w1t, b1, gate, perm, groupOff, z);
  k4a_down<<<dim3(4,16,4), 256, 0, stream>>>(z, W2, pooled);
  k4b_head<<<dim3(4,16), 256, 0, stream>>>(pooled, gateSum, b2, Wh, bh, out);
}

// Round 5
// 803.900 us; speedup vs baseline: 1.0344x; 1.0344x over previous
//
#include <hip/hip_runtime.h>
#include <hip/hip_bf16.h>
#include <stdint.h>

#define B_ 16
#define S_ 2048
#define D_ 1024
#define H_ 4096
#define E_ 4
#define C_ 1000

typedef __attribute__((ext_vector_type(8))) short short8;
typedef __attribute__((ext_vector_type(4))) float f32x4;

__device__ __forceinline__ unsigned short f2bf(float f){
  unsigned u = __float_as_uint(f);
  u += 0x7fffu + ((u>>16)&1u);
  return (unsigned short)(u>>16);
}

__device__ __forceinline__ void gload16(const void* g, void* l){
  __builtin_amdgcn_global_load_lds(
    (const __attribute__((address_space(1))) unsigned*)(uintptr_t)g,
    (__attribute__((address_space(3))) unsigned*)(uintptr_t)l, 16, 0, 0);
}

// ---------------- K0: W1 [E][D][H] fp32 -> W1T [E][H][D] bf16 ----------------
// 64x64 tile; float4 reads, ushort4 writes.
__global__ __launch_bounds__(256) void k0_transpose(const float* __restrict__ W1,
                                                    unsigned short* __restrict__ w1t){
  __shared__ float t[64][65];
  int tid = threadIdx.x;
  int h0 = blockIdx.x*64, d0 = blockIdx.y*64, e = blockIdx.z;
  const float* src = W1 + ((size_t)e*D_ + d0)*H_ + h0;
#pragma unroll
  for (int i=0;i<4;i++){
    int idx = i*256 + tid;
    int d = idx>>4, h4 = idx&15;
    float4 v = *(const float4*)&src[(size_t)d*H_ + h4*4];
    t[d][h4*4+0]=v.x; t[d][h4*4+1]=v.y; t[d][h4*4+2]=v.z; t[d][h4*4+3]=v.w;
  }
  __syncthreads();
  unsigned short* dst = w1t + ((size_t)e*H_ + h0)*D_ + d0;
#pragma unroll
  for (int i=0;i<4;i++){
    int idx = i*256 + tid;
    int h = idx>>4, d4 = idx&15;
    ushort4 o;
    o.x = f2bf(t[d4*4+0][h]); o.y = f2bf(t[d4*4+1][h]);
    o.z = f2bf(t[d4*4+2][h]); o.w = f2bf(t[d4*4+3][h]);
    *(ushort4*)&dst[(size_t)h*D_ + d4*4] = o;
  }
}

// ---------------- K1: gating (fp32) + x->bf16 cast ----------------
__global__ __launch_bounds__(256) void k1_gate(const float* __restrict__ x,
    const float* __restrict__ Wg, const float* __restrict__ bg,
    unsigned short* __restrict__ xbf, float* __restrict__ gate,
    int* __restrict__ eidx, float* __restrict__ probSum,
    unsigned* __restrict__ cntBE, float* __restrict__ gateSum){
  __shared__ float ps_l[4];
  __shared__ float gs_l[64];
  __shared__ unsigned cnt_l[64];
  int tid = threadIdx.x, lane = tid&63, wid = tid>>6;
  if (tid<4) ps_l[tid]=0.f;
  if (tid<64){ gs_l[tid]=0.f; cnt_l[tid]=0u; }
  __syncthreads();
  const float4* wg4 = (const float4*)Wg;   // wg4[d] = Wg[d][0..3]
  float4 wr[16];
#pragma unroll
  for (int k=0;k<4;k++)
#pragma unroll
    for (int c=0;c<4;c++) wr[k*4+c] = wg4[(lane + 64*k)*4 + c];
  float bgv0=bg[0], bgv1=bg[1], bgv2=bg[2], bgv3=bg[3];
  for (int it=0; it<16; ++it){
    int t = it*2048 + blockIdx.x*4 + wid;
    const float4* xr = (const float4*)(x + (size_t)t*D_);
    ushort4* xo = (ushort4*)(xbf + (size_t)t*D_);
    float4 acc = make_float4(0.f,0.f,0.f,0.f);
#pragma unroll
    for (int k=0;k<4;k++){
      float4 xv = xr[lane + 64*k];
      float4 w;
      w = wr[k*4+0]; acc.x += xv.x*w.x; acc.y += xv.x*w.y; acc.z += xv.x*w.z; acc.w += xv.x*w.w;
      w = wr[k*4+1]; acc.x += xv.y*w.x; acc.y += xv.y*w.y; acc.z += xv.y*w.z; acc.w += xv.y*w.w;
      w = wr[k*4+2]; acc.x += xv.z*w.x; acc.y += xv.z*w.y; acc.z += xv.z*w.z; acc.w += xv.z*w.w;
      w = wr[k*4+3]; acc.x += xv.w*w.x; acc.y += xv.w*w.y; acc.z += xv.w*w.z; acc.w += xv.w*w.w;
      ushort4 o; o.x=f2bf(xv.x); o.y=f2bf(xv.y); o.z=f2bf(xv.z); o.w=f2bf(xv.w);
      xo[lane + 64*k] = o;
    }
#pragma unroll
    for (int mk=32; mk; mk>>=1){
      acc.x += __shfl_xor(acc.x, mk);
      acc.y += __shfl_xor(acc.y, mk);
      acc.z += __shfl_xor(acc.z, mk);
      acc.w += __shfl_xor(acc.w, mk);
    }
    if (lane==0){
      float l0=acc.x+bgv0, l1=acc.y+bgv1, l2=acc.z+bgv2, l3=acc.w+bgv3;
      int idx=0; float mv=l0;
      if (l1>mv){mv=l1;idx=1;}
      if (l2>mv){mv=l2;idx=2;}
      if (l3>mv){mv=l3;idx=3;}
      float e0=__expf(l0-mv), e1=__expf(l1-mv), e2=__expf(l2-mv), e3=__expf(l3-mv);
      float inv = 1.0f/(e0+e1+e2+e3);
      float gv = inv;                       // exp(0)*inv = top-1 prob
      eidx[t]=idx; gate[t]=gv;
      atomicAdd(&ps_l[0], e0*inv); atomicAdd(&ps_l[1], e1*inv);
      atomicAdd(&ps_l[2], e2*inv); atomicAdd(&ps_l[3], e3*inv);
      int bb = t >> 11;                     // S=2048
      atomicAdd(&cnt_l[idx*16+bb], 1u);
      atomicAdd(&gs_l[idx*16+bb], gv);
    }
  }
  __syncthreads();
  if (tid<4) atomicAdd(&probSum[tid], ps_l[tid]);
  if (tid<64){ atomicAdd(&cntBE[tid], cnt_l[tid]); atomicAdd(&gateSum[tid], gs_l[tid]); }
}

// ---------------- K2a: offsets + aux loss ----------------
__global__ __launch_bounds__(64) void k2a_offsets(const unsigned* __restrict__ cntBE,
    const float* __restrict__ probSum, unsigned* __restrict__ groupOff,
    unsigned* __restrict__ cursor, float* __restrict__ out_aux){
  if (threadIdx.x==0){
    unsigned off=0;
    for (int g=0; g<64; ++g){ groupOff[g]=off; cursor[g*32]=off; off += cntBE[g]; }
    groupOff[64]=off;
    float aux=0.f;
    for (int e=0;e<4;e++){
      float ce=0.f;
      for (int b=0;b<16;b++) ce += (float)cntBE[e*16+b];
      aux += ce * probSum[e];
    }
    aux *= 4.0f/(32768.0f*32768.0f);
    *out_aux = aux;
  }
}

// ---------------- K2b: counting-sort scatter (also permuted gate) ----------------
__global__ __launch_bounds__(256) void k2b_scatter(const int* __restrict__ eidx,
   const float* __restrict__ gate, unsigned* __restrict__ cursor,
   int* __restrict__ perm, float* __restrict__ gateP){
  int t = blockIdx.x*256 + threadIdx.x;
  int e = eidx[t]; int bb = t>>11; int g = e*16+bb;
  unsigned pos = atomicAdd(&cursor[g*32], 1u);
  perm[pos] = (int)t;
  gateP[pos] = gate[t];
}

// ---------------- K3: grouped up-GEMM, dbuf LDS + counted vmcnt pipeline ----
// Per kt: STAGE(kt+1) -> vmcnt(8) -> barrier -> ds_read+MFMA(kt) -> barrier.
#define STAGE(BUF, KT) do{                                                              \
  _Pragma("unroll") for (int q=0;q<4;q++)                                               \
    gload16(xbf + (size_t)pm[q]*D_ + (KT)*64 + soff[q],                                 \
            (char*)&xs[BUF][0] + (q*4+w)*1024);                                         \
  _Pragma("unroll") for (int q=0;q<4;q++)                                               \
    gload16(w1t + wbase + (size_t)srow[q]*D_ + (KT)*64 + soff[q],                       \
            (char*)&wt[BUF][0] + (q*4+w)*1024);                                         \
}while(0)

#define KBODY(BUF, NW) do{                                                              \
  asm volatile("s_waitcnt vmcnt(" NW ")" ::: "memory");                                 \
  __builtin_amdgcn_s_barrier();                                                         \
  asm volatile("" ::: "memory");                                                        \
  _Pragma("unroll") for (int kk=0;kk<2;kk++){                                           \
    short8 af[4], bfr[4];                                                               \
    _Pragma("unroll") for (int rf=0;rf<4;rf++)                                          \
      af[rf] = *(const short8*)&xs[BUF][(rbase+rf*16+m)*64 + (((kk*4+p)^sw)<<3)];       \
    _Pragma("unroll") for (int cf=0;cf<4;cf++)                                          \
      bfr[cf] = *(const short8*)&wt[BUF][(cbase+cf*16+m)*64 + (((kk*4+p)^sw)<<3)];      \
    __builtin_amdgcn_s_setprio(1);                                                      \
    _Pragma("unroll") for (int rf=0;rf<4;rf++)                                          \
      _Pragma("unroll") for (int cf=0;cf<4;cf++)                                        \
        acc[rf][cf] = __builtin_amdgcn_mfma_f32_16x16x32_bf16(af[rf], bfr[cf], acc[rf][cf], 0,0,0); \
    __builtin_amdgcn_s_setprio(0);                                                      \
  }                                                                                     \
  asm volatile("" ::: "memory");                                                        \
  __builtin_amdgcn_s_barrier();                                                         \
}while(0)

__global__ __launch_bounds__(256) void k3_moe(const unsigned short* __restrict__ xbf,
    const unsigned short* __restrict__ w1t, const float* __restrict__ b1,
    const float* __restrict__ gateP, const int* __restrict__ perm,
    const unsigned* __restrict__ groupOff, float* __restrict__ z){
  __shared__ unsigned short xs[2][128*64];   // 32 KB
  __shared__ unsigned short wt[2][128*64];   // 32 KB  (total exactly 64 KB)
  int tid = threadIdx.x, lane = tid&63, w = tid>>6;
  int g = blockIdx.y;
  int e = g>>4;
  int col0 = blockIdx.x*128;
  int r0 = (int)groupOff[g];
  int cnt = (int)groupOff[g+1] - r0;
  if (cnt<=0) return;
  int m = lane&15, p = lane>>4, sw = m&7;
  int rbase = (w>>1)*64, cbase = (w&1)*64;
  size_t wbase = ((size_t)(e*H_ + col0))*D_;
  int srow[4], soff[4];
#pragma unroll
  for (int q=0;q<4;q++){
    int cidx = (q*4+w)*64 + lane;
    srow[q] = cidx>>3;
    soff[q] = ((cidx&7) ^ (srow[q]&7)) << 3;
  }
  float b1v[4];
#pragma unroll
  for (int cf=0;cf<4;cf++) b1v[cf] = b1[e*H_ + col0 + cbase + cf*16 + m];
  float zacc[4] = {0.f,0.f,0.f,0.f};
  int nchunk = (cnt+127)>>7;
  for (int ch=0; ch<nchunk; ++ch){
    int pm[4];
#pragma unroll
    for (int q=0;q<4;q++){
      int ri = ch*128 + srow[q];
      pm[q] = perm[r0 + (ri < cnt ? ri : cnt-1)];
    }
    float gv[4][4];
#pragma unroll
    for (int rf=0;rf<4;rf++)
#pragma unroll
      for (int j=0;j<4;j++){
        int row = ch*128 + rbase + rf*16 + p*4 + j;
        gv[rf][j] = (row < cnt) ? gateP[r0 + row] : 0.f;
      }
    f32x4 acc[4][4];
    f32x4 vz = {0.f,0.f,0.f,0.f};
#pragma unroll
    for (int a=0;a<4;a++)
#pragma unroll
      for (int c2=0;c2<4;c2++) acc[a][c2] = vz;
    STAGE(0, 0);
#pragma unroll
    for (int kp=0; kp<7; ++kp){
      STAGE(1, kp*2+1); KBODY(0, "8");
      STAGE(0, kp*2+2); KBODY(1, "8");
    }
    STAGE(1, 15); KBODY(0, "8");
    KBODY(1, "0");
    // epilogue: relu(h+b1)*gate, reduce rows into zacc (C layout: col=m, row=p*4+j)
#pragma unroll
    for (int rf=0;rf<4;rf++)
#pragma unroll
      for (int cf=0;cf<4;cf++){
        f32x4 a = acc[rf][cf];
        zacc[cf] += gv[rf][0]*fmaxf(a[0]+b1v[cf],0.f) + gv[rf][1]*fmaxf(a[1]+b1v[cf],0.f)
                  + gv[rf][2]*fmaxf(a[2]+b1v[cf],0.f) + gv[rf][3]*fmaxf(a[3]+b1v[cf],0.f);
      }
  }
#pragma unroll
  for (int cf=0;cf<4;cf++){
    float v = zacc[cf];
    v += __shfl_xor(v, 16);
    v += __shfl_xor(v, 32);
    if (p==0) atomicAdd(&z[(size_t)g*H_ + col0 + cbase + cf*16 + m], v);
  }
}

// ---------------- K4a: pooled += z @ W2 (fp32, memory-bound) ----------------
__global__ __launch_bounds__(256) void k4a_down(const float* __restrict__ z,
    const float* __restrict__ W2, float* __restrict__ pooled){
  __shared__ float zs[16*256];
  int tid = threadIdx.x;
  int d0 = blockIdx.x*256, j0 = blockIdx.y*256, e = blockIdx.z;
  for (int idx=tid; idx<4096; idx+=256){
    int bb = idx>>8, j = idx&255;
    zs[idx] = z[((size_t)(e*16+bb))*H_ + j0 + j];
  }
  __syncthreads();
  float acc[16];
#pragma unroll
  for (int bb=0;bb<16;bb++) acc[bb]=0.f;
  const float* w2b = W2 + ((size_t)e*H_ + j0)*D_ + d0 + tid;
  for (int j4=0; j4<256; j4+=4){
    float w0 = w2b[(size_t)(j4+0)*D_];
    float w1v= w2b[(size_t)(j4+1)*D_];
    float w2v= w2b[(size_t)(j4+2)*D_];
    float w3v= w2b[(size_t)(j4+3)*D_];
#pragma unroll
    for (int bb=0;bb<16;bb++){
      float4 zv = *(const float4*)&zs[bb*256 + j4];
      acc[bb] += zv.x*w0 + zv.y*w1v + zv.z*w2v + zv.w*w3v;
    }
  }
#pragma unroll
  for (int bb=0;bb<16;bb++) atomicAdd(&pooled[bb*D_ + d0 + tid], acc[bb]);
}

// ---------------- K4b: +bias term, /S, head GEMV (float4 along C) ----------------
__global__ __launch_bounds__(256) void k4b_head(const float* __restrict__ pooled,
    const float* __restrict__ gateSum, const float* __restrict__ b2,
    const float* __restrict__ Wh, const float* __restrict__ bh,
    float* __restrict__ out){
  __shared__ float plf[1024];
  int tid = threadIdx.x, bb = blockIdx.x;
  float gs0 = gateSum[0*16+bb], gs1 = gateSum[1*16+bb];
  float gs2 = gateSum[2*16+bb], gs3 = gateSum[3*16+bb];
  for (int d=tid; d<1024; d+=256){
    float pv = pooled[bb*D_ + d];
    pv += gs0*b2[0*D_+d] + gs1*b2[1*D_+d] + gs2*b2[2*D_+d] + gs3*b2[3*D_+d];
    plf[d] = pv * (1.0f/2048.0f);
  }
  __syncthreads();
  if (tid < 250){
    float4 acc = ((const float4*)bh)[tid];
    const float4* whp = (const float4*)Wh + tid;   // 250 float4 per row
#pragma unroll 8
    for (int d=0; d<1024; ++d){
      float pv = plf[d];
      float4 wv = whp[(size_t)d*250];
      acc.x += pv*wv.x; acc.y += pv*wv.y; acc.z += pv*wv.z; acc.w += pv*wv.w;
    }
    ((float4*)(out + (size_t)bb*C_))[tid] = acc;
  }
}

extern "C" void kernel_launch(void* const* d_in, const int* in_sizes, int n_in,
                              void* d_out, int out_size, void* d_ws, size_t ws_size,
                              hipStream_t stream){
  (void)in_sizes; (void)n_in; (void)out_size; (void)ws_size;
  const float* x  = (const float*)d_in[0];
  const float* Wg = (const float*)d_in[1];
  const float* bg = (const float*)d_in[2];
  const float* W1 = (const float*)d_in[3];
  const float* b1 = (const float*)d_in[4];
  const float* W2 = (const float*)d_in[5];
  const float* b2 = (const float*)d_in[6];
  const float* Wh = (const float*)d_in[7];
  const float* bh = (const float*)d_in[8];
  float* out = (float*)d_out;
  char* ws = (char*)d_ws;

  float*    probSum = (float*)(ws + 0);        // 4
  unsigned* cntBE   = (unsigned*)(ws + 64);    // 64  (g = e*16+b)
  float*    gateSum = (float*)(ws + 320);      // 64
  unsigned* groupOff= (unsigned*)(ws + 576);   // 65
  unsigned* cursor  = (unsigned*)(ws + 1024);  // 64, stride 32 (cacheline pad)
  float*    z       = (float*)(ws + 16384);    // 64*4096 fp32 = 1 MB
  float*    pooled  = (float*)(ws + 1064960);  // 16*1024 fp32
  unsigned short* xbf = (unsigned short*)(ws + 2097152);    // 67 MB bf16
  int*      perm    = (int*)(ws + 69206016);   // 32768
  float*    gate    = (float*)(ws + 69337088); // 32768
  int*      eidx    = (int*)(ws + 69468160);   // 32768
  float*    gateP   = (float*)(ws + 69599232); // 32768 (permuted gate)
  unsigned short* w1t = (unsigned short*)(ws + 69730304);   // 33.5 MB bf16

  hipMemsetAsync(ws, 0, 1130496, stream);   // zero accumulators + z + pooled
  k0_transpose<<<dim3(64,16,4), 256, 0, stream>>>(W1, w1t);
  k1_gate<<<512, 256, 0, stream>>>(x, Wg, bg, xbf, gate, eidx, probSum, cntBE, gateSum);
  k2a_offsets<<<1, 64, 0, stream>>>(cntBE, probSum, groupOff, cursor, out + 16000);
  k2b_scatter<<<128, 256, 0, stream>>>(eidx, gate, cursor, perm, gateP);
  k3_moe<<<dim3(32,64), 256, 0, stream>>>(xbf, w1t, b1, gateP, perm, groupOff, z);
  k4a_down<<<dim3(4,16,4), 256, 0, stream>>>(z, W2, pooled);
  k4b_head<<<16, 256, 0, stream>>>(pooled, gateSum, b2, Wh, bh, out);
}

// Round 6
// 735.607 us; speedup vs baseline: 1.1305x; 1.0928x over previous
//
#include <hip/hip_runtime.h>
#include <hip/hip_bf16.h>
#include <stdint.h>

#define B_ 16
#define S_ 2048
#define D_ 1024
#define H_ 4096
#define E_ 4
#define C_ 1000

typedef __attribute__((ext_vector_type(8))) short short8;
typedef __attribute__((ext_vector_type(4))) float f32x4;

__device__ __forceinline__ unsigned short f2bf(float f){
  unsigned u = __float_as_uint(f);
  u += 0x7fffu + ((u>>16)&1u);
  return (unsigned short)(u>>16);
}

__device__ __forceinline__ void gload16(const void* g, void* l){
  __builtin_amdgcn_global_load_lds(
    (const __attribute__((address_space(1))) unsigned*)(uintptr_t)g,
    (__attribute__((address_space(3))) unsigned*)(uintptr_t)l, 16, 0, 0);
}

// ---------------- K0: W1 [E][D][H] fp32 -> W1T [E][H][D] bf16 ----------------
__global__ __launch_bounds__(256) void k0_transpose(const float* __restrict__ W1,
                                                    unsigned short* __restrict__ w1t){
  __shared__ float t[64][65];
  int tid = threadIdx.x;
  int h0 = blockIdx.x*64, d0 = blockIdx.y*64, e = blockIdx.z;
  const float* src = W1 + ((size_t)e*D_ + d0)*H_ + h0;
#pragma unroll
  for (int i=0;i<4;i++){
    int idx = i*256 + tid;
    int d = idx>>4, h4 = idx&15;
    float4 v = *(const float4*)&src[(size_t)d*H_ + h4*4];
    t[d][h4*4+0]=v.x; t[d][h4*4+1]=v.y; t[d][h4*4+2]=v.z; t[d][h4*4+3]=v.w;
  }
  __syncthreads();
  unsigned short* dst = w1t + ((size_t)e*H_ + h0)*D_ + d0;
#pragma unroll
  for (int i=0;i<4;i++){
    int idx = i*256 + tid;
    int h = idx>>4, d4 = idx&15;
    ushort4 o;
    o.x = f2bf(t[d4*4+0][h]); o.y = f2bf(t[d4*4+1][h]);
    o.z = f2bf(t[d4*4+2][h]); o.w = f2bf(t[d4*4+3][h]);
    *(ushort4*)&dst[(size_t)h*D_ + d4*4] = o;
  }
}

// ---------------- K1: gating (fp32) + x->bf16 cast ----------------
__global__ __launch_bounds__(256) void k1_gate(const float* __restrict__ x,
    const float* __restrict__ Wg, const float* __restrict__ bg,
    unsigned short* __restrict__ xbf, float* __restrict__ gate,
    int* __restrict__ eidx, float* __restrict__ probSum,
    unsigned* __restrict__ cntBE, float* __restrict__ gateSum){
  __shared__ float ps_l[4];
  __shared__ float gs_l[64];
  __shared__ unsigned cnt_l[64];
  int tid = threadIdx.x, lane = tid&63, wid = tid>>6;
  if (tid<4) ps_l[tid]=0.f;
  if (tid<64){ gs_l[tid]=0.f; cnt_l[tid]=0u; }
  __syncthreads();
  const float4* wg4 = (const float4*)Wg;
  float4 wr[16];
#pragma unroll
  for (int k=0;k<4;k++)
#pragma unroll
    for (int c=0;c<4;c++) wr[k*4+c] = wg4[(lane + 64*k)*4 + c];
  float bgv0=bg[0], bgv1=bg[1], bgv2=bg[2], bgv3=bg[3];
  for (int it=0; it<16; ++it){
    int t = it*2048 + blockIdx.x*4 + wid;
    const float4* xr = (const float4*)(x + (size_t)t*D_);
    ushort4* xo = (ushort4*)(xbf + (size_t)t*D_);
    float4 acc = make_float4(0.f,0.f,0.f,0.f);
#pragma unroll
    for (int k=0;k<4;k++){
      float4 xv = xr[lane + 64*k];
      float4 w;
      w = wr[k*4+0]; acc.x += xv.x*w.x; acc.y += xv.x*w.y; acc.z += xv.x*w.z; acc.w += xv.x*w.w;
      w = wr[k*4+1]; acc.x += xv.y*w.x; acc.y += xv.y*w.y; acc.z += xv.y*w.z; acc.w += xv.y*w.w;
      w = wr[k*4+2]; acc.x += xv.z*w.x; acc.y += xv.z*w.y; acc.z += xv.z*w.z; acc.w += xv.z*w.w;
      w = wr[k*4+3]; acc.x += xv.w*w.x; acc.y += xv.w*w.y; acc.z += xv.w*w.z; acc.w += xv.w*w.w;
      ushort4 o; o.x=f2bf(xv.x); o.y=f2bf(xv.y); o.z=f2bf(xv.z); o.w=f2bf(xv.w);
      xo[lane + 64*k] = o;
    }
#pragma unroll
    for (int mk=32; mk; mk>>=1){
      acc.x += __shfl_xor(acc.x, mk);
      acc.y += __shfl_xor(acc.y, mk);
      acc.z += __shfl_xor(acc.z, mk);
      acc.w += __shfl_xor(acc.w, mk);
    }
    if (lane==0){
      float l0=acc.x+bgv0, l1=acc.y+bgv1, l2=acc.z+bgv2, l3=acc.w+bgv3;
      int idx=0; float mv=l0;
      if (l1>mv){mv=l1;idx=1;}
      if (l2>mv){mv=l2;idx=2;}
      if (l3>mv){mv=l3;idx=3;}
      float e0=__expf(l0-mv), e1=__expf(l1-mv), e2=__expf(l2-mv), e3=__expf(l3-mv);
      float inv = 1.0f/(e0+e1+e2+e3);
      float gv = inv;
      eidx[t]=idx; gate[t]=gv;
      atomicAdd(&ps_l[0], e0*inv); atomicAdd(&ps_l[1], e1*inv);
      atomicAdd(&ps_l[2], e2*inv); atomicAdd(&ps_l[3], e3*inv);
      int bb = t >> 11;
      atomicAdd(&cnt_l[idx*16+bb], 1u);
      atomicAdd(&gs_l[idx*16+bb], gv);
    }
  }
  __syncthreads();
  if (tid<4) atomicAdd(&probSum[tid], ps_l[tid]);
  if (tid<64){ atomicAdd(&cntBE[tid], cnt_l[tid]); atomicAdd(&gateSum[tid], gs_l[tid]); }
}

// ---------------- K2a: offsets + aux loss ----------------
__global__ __launch_bounds__(64) void k2a_offsets(const unsigned* __restrict__ cntBE,
    const float* __restrict__ probSum, unsigned* __restrict__ groupOff,
    unsigned* __restrict__ cursor, float* __restrict__ out_aux){
  if (threadIdx.x==0){
    unsigned off=0;
    for (int g=0; g<64; ++g){ groupOff[g]=off; cursor[g*32]=off; off += cntBE[g]; }
    groupOff[64]=off;
    float aux=0.f;
    for (int e=0;e<4;e++){
      float ce=0.f;
      for (int b=0;b<16;b++) ce += (float)cntBE[e*16+b];
      aux += ce * probSum[e];
    }
    aux *= 4.0f/(32768.0f*32768.0f);
    *out_aux = aux;
  }
}

// ---------------- K2b: counting-sort scatter (also permuted gate) ----------------
__global__ __launch_bounds__(256) void k2b_scatter(const int* __restrict__ eidx,
   const float* __restrict__ gate, unsigned* __restrict__ cursor,
   int* __restrict__ perm, float* __restrict__ gateP){
  int t = blockIdx.x*256 + threadIdx.x;
  int e = eidx[t]; int bb = t>>11; int g = e*16+bb;
  unsigned pos = atomicAdd(&cursor[g*32], 1u);
  perm[pos] = (int)t;
  gateP[pos] = gate[t];
}

// ---------------- K3: grouped up-GEMM, 256x256 tile, 8 waves, deep-lead pipe --
// Per K-tile: [vmcnt(0) (lead = full prior tile ~2500cy, so ~free); barrier;
//   issue ALL 8 gloads of tile kt+1 into buf^1; 4x{ds_read subset; setprio1;
//   16 MFMA; setprio0}]. One barrier per K-tile. 128KB LDS, 1 block/CU.
#define STAGE(BUF, KT) do{                                                       \
  _Pragma("unroll") for (int q=0;q<4;q++)                                        \
    gload16(srcA[q] + (KT)*64, (char*)As + (BUF)*32768 + (q*512+tid)*16);        \
  _Pragma("unroll") for (int q=0;q<4;q++)                                        \
    gload16(srcB[q] + (KT)*64, (char*)Bs + (BUF)*32768 + (q*512+tid)*16);        \
}while(0)

__global__ __launch_bounds__(512, 2) void k3_moe(const unsigned short* __restrict__ xbf,
    const unsigned short* __restrict__ w1t, const float* __restrict__ b1,
    const float* __restrict__ gateP, const int* __restrict__ perm,
    const unsigned* __restrict__ groupOff, float* __restrict__ z){
  __shared__ unsigned short As[2][256][64];   // 64 KB
  __shared__ unsigned short Bs[2][256][64];   // 64 KB
  int tid = threadIdx.x, lane = tid&63, wid = tid>>6;
  int wr = wid>>2, wc = wid&3;                 // 2M x 4N wave grid
  int m = lane&15, p = lane>>4, sw = m&7;
  int g = blockIdx.y, e = g>>4, col0 = blockIdx.x*256, ch = blockIdx.z;
  int r0 = (int)groupOff[g];
  int cnt = (int)groupOff[g+1] - r0;
  if (ch*256 >= cnt) return;
  // staging addresses (fixed per thread; only K offset advances)
  int rld = tid>>3, ci = tid&7;
  int soff = (ci ^ (rld&7))<<3;                // XOR swizzle on SOURCE (rule #21)
  const unsigned short* srcA[4];
  const unsigned short* srcB[4];
#pragma unroll
  for (int q=0;q<4;q++){
    int rowq = q*64 + rld;
    int ri = ch*256 + rowq; if (ri >= cnt) ri = cnt-1;
    srcA[q] = xbf + (size_t)perm[r0 + ri]*D_ + soff;
    srcB[q] = w1t + ((size_t)(e*H_ + col0 + rowq))*D_ + soff;
  }
  float b1v[4];
#pragma unroll
  for (int cf=0;cf<4;cf++) b1v[cf] = b1[e*H_ + col0 + wc*64 + cf*16 + m];
  f32x4 acc[8][4];
  f32x4 vz = {0.f,0.f,0.f,0.f};
#pragma unroll
  for (int a=0;a<8;a++)
#pragma unroll
    for (int c2=0;c2<4;c2++) acc[a][c2] = vz;

  STAGE(0, 0);
#pragma unroll 2
  for (int kt=0; kt<16; ++kt){
    int buf = kt&1;
    asm volatile("s_waitcnt vmcnt(0)" ::: "memory");
    __builtin_amdgcn_s_barrier();
    asm volatile("" ::: "memory");
    if (kt<15) STAGE(buf^1, kt+1);
#pragma unroll
    for (int kk=0;kk<2;kk++){
      int koff = ((kk*4+p)^sw)<<3;
      short8 bfr[4];
#pragma unroll
      for (int cf=0;cf<4;cf++)
        bfr[cf] = *(const short8*)&Bs[buf][wc*64 + cf*16 + m][koff];
#pragma unroll
      for (int rh=0;rh<2;rh++){
        short8 af[4];
#pragma unroll
        for (int rf=0;rf<4;rf++)
          af[rf] = *(const short8*)&As[buf][wr*128 + (rh*4+rf)*16 + m][koff];
        __builtin_amdgcn_s_setprio(1);
#pragma unroll
        for (int rf=0;rf<4;rf++)
#pragma unroll
          for (int cf=0;cf<4;cf++)
            acc[rh*4+rf][cf] = __builtin_amdgcn_mfma_f32_16x16x32_bf16(af[rf], bfr[cf], acc[rh*4+rf][cf], 0,0,0);
        __builtin_amdgcn_s_setprio(0);
      }
    }
  }
  // epilogue: relu(h+b1)*gate, reduce 128 wave-rows into zacc per col
  float zacc[4] = {0.f,0.f,0.f,0.f};
#pragma unroll
  for (int rf=0;rf<8;rf++){
    int rb = ch*256 + wr*128 + rf*16 + p*4;
    float gv[4];
#pragma unroll
    for (int j=0;j<4;j++){
      int row = rb + j;
      gv[j] = (row < cnt) ? gateP[r0 + row] : 0.f;
    }
#pragma unroll
    for (int cf=0;cf<4;cf++){
      f32x4 a = acc[rf][cf];
      zacc[cf] += gv[0]*fmaxf(a[0]+b1v[cf],0.f) + gv[1]*fmaxf(a[1]+b1v[cf],0.f)
                + gv[2]*fmaxf(a[2]+b1v[cf],0.f) + gv[3]*fmaxf(a[3]+b1v[cf],0.f);
    }
  }
#pragma unroll
  for (int cf=0;cf<4;cf++){
    float v = zacc[cf];
    v += __shfl_xor(v, 16);
    v += __shfl_xor(v, 32);
    if (p==0) atomicAdd(&z[(size_t)g*H_ + col0 + wc*64 + cf*16 + m], v);
  }
}

// ---------------- K4a: pooled += z @ W2 (fp32, memory-bound) ----------------
__global__ __launch_bounds__(256) void k4a_down(const float* __restrict__ z,
    const float* __restrict__ W2, float* __restrict__ pooled){
  __shared__ float zs[16*256];
  int tid = threadIdx.x;
  int d0 = blockIdx.x*256, j0 = blockIdx.y*256, e = blockIdx.z;
  for (int idx=tid; idx<4096; idx+=256){
    int bb = idx>>8, j = idx&255;
    zs[idx] = z[((size_t)(e*16+bb))*H_ + j0 + j];
  }
  __syncthreads();
  float acc[16];
#pragma unroll
  for (int bb=0;bb<16;bb++) acc[bb]=0.f;
  const float* w2b = W2 + ((size_t)e*H_ + j0)*D_ + d0 + tid;
  for (int j4=0; j4<256; j4+=4){
    float w0 = w2b[(size_t)(j4+0)*D_];
    float w1v= w2b[(size_t)(j4+1)*D_];
    float w2v= w2b[(size_t)(j4+2)*D_];
    float w3v= w2b[(size_t)(j4+3)*D_];
#pragma unroll
    for (int bb=0;bb<16;bb++){
      float4 zv = *(const float4*)&zs[bb*256 + j4];
      acc[bb] += zv.x*w0 + zv.y*w1v + zv.z*w2v + zv.w*w3v;
    }
  }
#pragma unroll
  for (int bb=0;bb<16;bb++) atomicAdd(&pooled[bb*D_ + d0 + tid], acc[bb]);
}

// ---------------- K4b: +bias term, /S, head GEMV (float4 along C) ----------------
__global__ __launch_bounds__(256) void k4b_head(const float* __restrict__ pooled,
    const float* __restrict__ gateSum, const float* __restrict__ b2,
    const float* __restrict__ Wh, const float* __restrict__ bh,
    float* __restrict__ out){
  __shared__ float plf[1024];
  int tid = threadIdx.x, bb = blockIdx.x;
  float gs0 = gateSum[0*16+bb], gs1 = gateSum[1*16+bb];
  float gs2 = gateSum[2*16+bb], gs3 = gateSum[3*16+bb];
  for (int d=tid; d<1024; d+=256){
    float pv = pooled[bb*D_ + d];
    pv += gs0*b2[0*D_+d] + gs1*b2[1*D_+d] + gs2*b2[2*D_+d] + gs3*b2[3*D_+d];
    plf[d] = pv * (1.0f/2048.0f);
  }
  __syncthreads();
  if (tid < 250){
    float4 acc = ((const float4*)bh)[tid];
    const float4* whp = (const float4*)Wh + tid;
#pragma unroll 8
    for (int d=0; d<1024; ++d){
      float pv = plf[d];
      float4 wv = whp[(size_t)d*250];
      acc.x += pv*wv.x; acc.y += pv*wv.y; acc.z += pv*wv.z; acc.w += pv*wv.w;
    }
    ((float4*)(out + (size_t)bb*C_))[tid] = acc;
  }
}

extern "C" void kernel_launch(void* const* d_in, const int* in_sizes, int n_in,
                              void* d_out, int out_size, void* d_ws, size_t ws_size,
                              hipStream_t stream){
  (void)in_sizes; (void)n_in; (void)out_size; (void)ws_size;
  const float* x  = (const float*)d_in[0];
  const float* Wg = (const float*)d_in[1];
  const float* bg = (const float*)d_in[2];
  const float* W1 = (const float*)d_in[3];
  const float* b1 = (const float*)d_in[4];
  const float* W2 = (const float*)d_in[5];
  const float* b2 = (const float*)d_in[6];
  const float* Wh = (const float*)d_in[7];
  const float* bh = (const float*)d_in[8];
  float* out = (float*)d_out;
  char* ws = (char*)d_ws;

  float*    probSum = (float*)(ws + 0);
  unsigned* cntBE   = (unsigned*)(ws + 64);
  float*    gateSum = (float*)(ws + 320);
  unsigned* groupOff= (unsigned*)(ws + 576);
  unsigned* cursor  = (unsigned*)(ws + 1024);
  float*    z       = (float*)(ws + 16384);
  float*    pooled  = (float*)(ws + 1064960);
  unsigned short* xbf = (unsigned short*)(ws + 2097152);
  int*      perm    = (int*)(ws + 69206016);
  float*    gate    = (float*)(ws + 69337088);
  int*      eidx    = (int*)(ws + 69468160);
  float*    gateP   = (float*)(ws + 69599232);
  unsigned short* w1t = (unsigned short*)(ws + 69730304);

  hipMemsetAsync(ws, 0, 1130496, stream);
  k0_transpose<<<dim3(64,16,4), 256, 0, stream>>>(W1, w1t);
  k1_gate<<<512, 256, 0, stream>>>(x, Wg, bg, xbf, gate, eidx, probSum, cntBE, gateSum);
  k2a_offsets<<<1, 64, 0, stream>>>(cntBE, probSum, groupOff, cursor, out + 16000);
  k2b_scatter<<<128, 256, 0, stream>>>(eidx, gate, cursor, perm, gateP);
  k3_moe<<<dim3(16,64,8), 512, 0, stream>>>(xbf, w1t, b1, gateP, perm, groupOff, z);
  k4a_down<<<dim3(4,16,4), 256, 0, stream>>>(z, W2, pooled);
  k4b_head<<<16, 256, 0, stream>>>(pooled, gateSum, b2, Wh, bh, out);
}

// Round 7
// 692.225 us; speedup vs baseline: 1.2013x; 1.0627x over previous
//
#include <hip/hip_runtime.h>
#include <hip/hip_bf16.h>
#include <stdint.h>

#define B_ 16
#define S_ 2048
#define D_ 1024
#define H_ 4096
#define E_ 4
#define C_ 1000

typedef __attribute__((ext_vector_type(8))) short short8;
typedef __attribute__((ext_vector_type(4))) float f32x4;

__device__ __forceinline__ unsigned short f2bf(float f){
  unsigned u = __float_as_uint(f);
  u += 0x7fffu + ((u>>16)&1u);
  return (unsigned short)(u>>16);
}

__device__ __forceinline__ void gload16(const void* g, void* l){
  __builtin_amdgcn_global_load_lds(
    (const __attribute__((address_space(1))) unsigned*)(uintptr_t)g,
    (__attribute__((address_space(3))) unsigned*)(uintptr_t)l, 16, 0, 0);
}

// ---------------- K0: W1 [E][D][H] fp32 -> W1T [E][H][D] bf16 ----------------
__global__ __launch_bounds__(256) void k0_transpose(const float* __restrict__ W1,
                                                    unsigned short* __restrict__ w1t){
  __shared__ float t[64][65];
  int tid = threadIdx.x;
  int h0 = blockIdx.x*64, d0 = blockIdx.y*64, e = blockIdx.z;
  const float* src = W1 + ((size_t)e*D_ + d0)*H_ + h0;
#pragma unroll
  for (int i=0;i<4;i++){
    int idx = i*256 + tid;
    int d = idx>>4, h4 = idx&15;
    float4 v = *(const float4*)&src[(size_t)d*H_ + h4*4];
    t[d][h4*4+0]=v.x; t[d][h4*4+1]=v.y; t[d][h4*4+2]=v.z; t[d][h4*4+3]=v.w;
  }
  __syncthreads();
  unsigned short* dst = w1t + ((size_t)e*H_ + h0)*D_ + d0;
#pragma unroll
  for (int i=0;i<4;i++){
    int idx = i*256 + tid;
    int h = idx>>4, d4 = idx&15;
    ushort4 o;
    o.x = f2bf(t[d4*4+0][h]); o.y = f2bf(t[d4*4+1][h]);
    o.z = f2bf(t[d4*4+2][h]); o.w = f2bf(t[d4*4+3][h]);
    *(ushort4*)&dst[(size_t)h*D_ + d4*4] = o;
  }
}

// ---------------- K1: gating GEMV (fp32) + x->bf16 cast; logits only ----------
__global__ __launch_bounds__(256) void k1_gate(const float* __restrict__ x,
    const float* __restrict__ Wg, unsigned short* __restrict__ xbf,
    float4* __restrict__ logits4){
  int tid = threadIdx.x, lane = tid&63, wid = tid>>6;
  const float4* wg4 = (const float4*)Wg;
  float4 wr[16];
#pragma unroll
  for (int k=0;k<4;k++)
#pragma unroll
    for (int c=0;c<4;c++) wr[k*4+c] = wg4[(lane + 64*k)*4 + c];
  for (int it=0; it<16; ++it){
    int t = it*2048 + blockIdx.x*4 + wid;
    const float4* xr = (const float4*)(x + (size_t)t*D_);
    ushort4* xo = (ushort4*)(xbf + (size_t)t*D_);
    float4 acc = make_float4(0.f,0.f,0.f,0.f);
#pragma unroll
    for (int k=0;k<4;k++){
      float4 xv = xr[lane + 64*k];
      float4 w;
      w = wr[k*4+0]; acc.x += xv.x*w.x; acc.y += xv.x*w.y; acc.z += xv.x*w.z; acc.w += xv.x*w.w;
      w = wr[k*4+1]; acc.x += xv.y*w.x; acc.y += xv.y*w.y; acc.z += xv.y*w.z; acc.w += xv.y*w.w;
      w = wr[k*4+2]; acc.x += xv.z*w.x; acc.y += xv.z*w.y; acc.z += xv.z*w.z; acc.w += xv.z*w.w;
      w = wr[k*4+3]; acc.x += xv.w*w.x; acc.y += xv.w*w.y; acc.z += xv.w*w.z; acc.w += xv.w*w.w;
      ushort4 o; o.x=f2bf(xv.x); o.y=f2bf(xv.y); o.z=f2bf(xv.z); o.w=f2bf(xv.w);
      xo[lane + 64*k] = o;
    }
#pragma unroll
    for (int mk=32; mk; mk>>=1){
      acc.x += __shfl_xor(acc.x, mk);
      acc.y += __shfl_xor(acc.y, mk);
      acc.z += __shfl_xor(acc.z, mk);
      acc.w += __shfl_xor(acc.w, mk);
    }
    if (lane==0) logits4[t] = acc;
  }
}

// ---------------- K1b: per-token softmax/argmax + routing stats ---------------
__global__ __launch_bounds__(256) void k1b_route(const float4* __restrict__ logits4,
    const float* __restrict__ bg, float* __restrict__ gate, int* __restrict__ eidx,
    float* __restrict__ probSum, unsigned* __restrict__ cntBE,
    float* __restrict__ gateSum){
  __shared__ float ps_l[4], gs_l[4];
  __shared__ unsigned cn_l[4];
  int tid = threadIdx.x, lane = tid&63;
  if (tid<4){ ps_l[tid]=0.f; gs_l[tid]=0.f; cn_l[tid]=0u; }
  __syncthreads();
  int t = blockIdx.x*256 + tid;
  int bb = t>>11;                           // uniform per block
  float4 l = logits4[t];
  float l0=l.x+bg[0], l1=l.y+bg[1], l2=l.z+bg[2], l3=l.w+bg[3];
  int idx=0; float mv=l0;
  if (l1>mv){mv=l1;idx=1;}
  if (l2>mv){mv=l2;idx=2;}
  if (l3>mv){mv=l3;idx=3;}
  float e0=__expf(l0-mv), e1=__expf(l1-mv), e2=__expf(l2-mv), e3=__expf(l3-mv);
  float inv = 1.0f/(e0+e1+e2+e3);
  float gv = inv;
  eidx[t]=idx; gate[t]=gv;
  float pr[4]={e0*inv, e1*inv, e2*inv, e3*inv};
#pragma unroll
  for (int e=0;e<4;e++){
    float pv = pr[e];
    float gm = (idx==e) ? gv : 0.f;
    unsigned long long mk2 = __ballot(idx==e);
#pragma unroll
    for (int mk=32; mk; mk>>=1){
      pv += __shfl_xor(pv, mk);
      gm += __shfl_xor(gm, mk);
    }
    if (lane==0){
      atomicAdd(&ps_l[e], pv); atomicAdd(&gs_l[e], gm);
      atomicAdd(&cn_l[e], (unsigned)__popcll(mk2));
    }
  }
  __syncthreads();
  if (tid<4){
    atomicAdd(&probSum[tid], ps_l[tid]);
    atomicAdd(&gateSum[tid*16+bb], gs_l[tid]);
    atomicAdd(&cntBE[tid*16+bb], cn_l[tid]);
  }
}

// ---------------- K2a: offsets + expert tile table + aux loss ----------------
__global__ __launch_bounds__(64) void k2a_offsets(const unsigned* __restrict__ cntBE,
    const float* __restrict__ probSum, unsigned* __restrict__ groupOff,
    unsigned* __restrict__ cursor, int* __restrict__ expertOff,
    int* __restrict__ tileTab, float* __restrict__ out_aux){
  if (threadIdx.x==0){
    unsigned off=0;
    for (int g=0; g<64; ++g){ groupOff[g]=off; cursor[g*32]=off; off += cntBE[g]; }
    groupOff[64]=off;
#pragma unroll
    for (int e=0;e<4;e++) expertOff[e] = (int)groupOff[e*16];
    expertOff[4] = (int)off;
    int nt=0;
    for (int e=0;e<4;e++){
      int base = expertOff[e], cnt = expertOff[e+1]-base;
      for (int c=0; c*256<cnt; ++c) tileTab[nt++] = ((base+c*256)<<3) | (e<<1) | 1;
    }
    float aux=0.f;
    for (int e=0;e<4;e++){
      float ce=0.f;
      for (int b=0;b<16;b++) ce += (float)cntBE[e*16+b];
      aux += ce * probSum[e];
    }
    aux *= 4.0f/(32768.0f*32768.0f);
    *out_aux = aux;
  }
}

// ---------------- K2b: counting-sort scatter (64 groups -> (e,b)-sorted perm) --
__global__ __launch_bounds__(256) void k2b_scatter(const int* __restrict__ eidx,
   const float* __restrict__ gate, unsigned* __restrict__ cursor,
   int* __restrict__ perm, float* __restrict__ gateP){
  int t = blockIdx.x*256 + threadIdx.x;
  int e = eidx[t]; int bb = t>>11; int g = e*16+bb;
  unsigned pos = atomicAdd(&cursor[g*32], 1u);
  perm[pos] = (int)t;
  gateP[pos] = gate[t];
}

// ---------------- K3: grouped up-GEMM, 256x256, XCD-clustered tiles -----------
#define STAGE(BUF, KT) do{                                                       \
  _Pragma("unroll") for (int q=0;q<4;q++)                                        \
    gload16(srcA[q] + (KT)*64, (char*)As + (BUF)*32768 + (q*512+tid)*16);        \
  _Pragma("unroll") for (int q=0;q<4;q++)                                        \
    gload16(srcB[q] + (KT)*64, (char*)Bs + (BUF)*32768 + (q*512+tid)*16);        \
}while(0)

__global__ __launch_bounds__(512, 2) void k3_moe(const unsigned short* __restrict__ xbf,
    const unsigned short* __restrict__ w1t, const float* __restrict__ b1,
    const float* __restrict__ gateP, const int* __restrict__ perm,
    const int* __restrict__ expertOff, const int* __restrict__ tileTab,
    float* __restrict__ z){
  __shared__ unsigned short As[2][256][64];   // 64 KB
  __shared__ unsigned short Bs[2][256][64];   // 64 KB
  int tid = threadIdx.x, lane = tid&63, wid = tid>>6;
  // XCD-clustered decode: each tile_m's 16 cols split over 2 fixed XCDs (8 each)
  int wgid = blockIdx.x;
  int xcd = wgid&7, rest = wgid>>3;
  int tile_m = (rest>>3)*4 + (xcd>>1);
  int col = (xcd&1)*8 + (rest&7);
  int te = tileTab[tile_m];
  if (!(te&1)) return;
  int e = (te>>1)&3;
  int rowStart = te>>3;
  int rowEnd = expertOff[e+1];
  int col0 = col*256;
  int wr = wid>>2, wc = wid&3;
  int m = lane&15, p = lane>>4, sw = m&7;
  int rld = tid>>3, ci = tid&7;
  int soff = (ci ^ (rld&7))<<3;               // XOR swizzle on SOURCE
  const unsigned short* srcA[4];
  const unsigned short* srcB[4];
#pragma unroll
  for (int q=0;q<4;q++){
    int rowq = q*64 + rld;
    int ri = rowStart + rowq; if (ri >= rowEnd) ri = rowEnd-1;
    srcA[q] = xbf + (size_t)perm[ri]*D_ + soff;
    srcB[q] = w1t + ((size_t)(e*H_ + col0 + rowq))*D_ + soff;
  }
  f32x4 acc[8][4];
  f32x4 vz = {0.f,0.f,0.f,0.f};
#pragma unroll
  for (int a=0;a<8;a++)
#pragma unroll
    for (int c2=0;c2<4;c2++) acc[a][c2] = vz;

  STAGE(0, 0);
#pragma unroll 2
  for (int kt=0; kt<16; ++kt){
    int buf = kt&1;
    asm volatile("s_waitcnt vmcnt(0)" ::: "memory");
    __builtin_amdgcn_s_barrier();
    asm volatile("" ::: "memory");
    if (kt<15) STAGE(buf^1, kt+1);
#pragma unroll
    for (int kk=0;kk<2;kk++){
      int koff = ((kk*4+p)^sw)<<3;
      short8 bfr[4];
#pragma unroll
      for (int cf=0;cf<4;cf++)
        bfr[cf] = *(const short8*)&Bs[buf][wc*64 + cf*16 + m][koff];
#pragma unroll
      for (int rh=0;rh<2;rh++){
        short8 af[4];
#pragma unroll
        for (int rf=0;rf<4;rf++)
          af[rf] = *(const short8*)&As[buf][wr*128 + (rh*4+rf)*16 + m][koff];
        __builtin_amdgcn_s_setprio(1);
#pragma unroll
        for (int rf=0;rf<4;rf++)
#pragma unroll
          for (int cf=0;cf<4;cf++)
            acc[rh*4+rf][cf] = __builtin_amdgcn_mfma_f32_16x16x32_bf16(af[rf], bfr[cf], acc[rh*4+rf][cf], 0,0,0);
        __builtin_amdgcn_s_setprio(0);
      }
    }
  }
  // epilogue: per-row b-masked relu/gate reduction into z[e*16+b]
  float b1v[4];
#pragma unroll
  for (int cf=0;cf<4;cf++) b1v[cf] = b1[e*H_ + col0 + wc*64 + cf*16 + m];
  float gv[8][4]; int bP[8];
  int bmin=15, bmax=0;
#pragma unroll
  for (int rf=0;rf<8;rf++){
    bP[rf]=0;
#pragma unroll
    for (int j=0;j<4;j++){
      int row = rowStart + wr*128 + rf*16 + p*4 + j;
      int real = row < rowEnd;
      int rr = real ? row : rowEnd-1;
      float gvv = real ? gateP[rr] : 0.f;
      int bb = perm[rr]>>11;
      gv[rf][j] = gvv; bP[rf] |= bb<<(4*j);
      bmin = min(bmin, bb); bmax = max(bmax, bb);
    }
  }
  bmin = min(bmin, __shfl_xor(bmin,16)); bmin = min(bmin, __shfl_xor(bmin,32));
  bmax = max(bmax, __shfl_xor(bmax,16)); bmax = max(bmax, __shfl_xor(bmax,32));
  for (int bv=bmin; bv<=bmax; ++bv){
    float zacc[4] = {0.f,0.f,0.f,0.f};
#pragma unroll
    for (int rf=0;rf<8;rf++){
      float w0 = (((bP[rf]>>0 )&15)==bv) ? gv[rf][0] : 0.f;
      float w1 = (((bP[rf]>>4 )&15)==bv) ? gv[rf][1] : 0.f;
      float w2 = (((bP[rf]>>8 )&15)==bv) ? gv[rf][2] : 0.f;
      float w3 = (((bP[rf]>>12)&15)==bv) ? gv[rf][3] : 0.f;
#pragma unroll
      for (int cf=0;cf<4;cf++){
        f32x4 a = acc[rf][cf];
        zacc[cf] += w0*fmaxf(a[0]+b1v[cf],0.f) + w1*fmaxf(a[1]+b1v[cf],0.f)
                  + w2*fmaxf(a[2]+b1v[cf],0.f) + w3*fmaxf(a[3]+b1v[cf],0.f);
      }
    }
#pragma unroll
    for (int cf=0;cf<4;cf++){
      float v = zacc[cf];
      v += __shfl_xor(v, 16);
      v += __shfl_xor(v, 32);
      if (p==0) atomicAdd(&z[(size_t)(e*16+bv)*H_ + col0 + wc*64 + cf*16 + m], v);
    }
  }
}

// ---------------- K4a: partial[e,j0][bb][:] = z-chunk @ W2-chunk --------------
__global__ __launch_bounds__(256) void k4a_down(const float* __restrict__ z,
    const float* __restrict__ W2, float* __restrict__ partial){
  __shared__ float zs[16*256];
  int tid = threadIdx.x;
  int d0 = blockIdx.x*256, j0 = blockIdx.y*256, e = blockIdx.z;
  for (int idx=tid; idx<4096; idx+=256){
    int bb = idx>>8, j = idx&255;
    zs[idx] = z[((size_t)(e*16+bb))*H_ + j0 + j];
  }
  __syncthreads();
  float acc[16];
#pragma unroll
  for (int bb=0;bb<16;bb++) acc[bb]=0.f;
  const float* w2b = W2 + ((size_t)e*H_ + j0)*D_ + d0 + tid;
  for (int j4=0; j4<256; j4+=4){
    float w0 = w2b[(size_t)(j4+0)*D_];
    float w1v= w2b[(size_t)(j4+1)*D_];
    float w2v= w2b[(size_t)(j4+2)*D_];
    float w3v= w2b[(size_t)(j4+3)*D_];
#pragma unroll
    for (int bb=0;bb<16;bb++){
      float4 zv = *(const float4*)&zs[bb*256 + j4];
      acc[bb] += zv.x*w0 + zv.y*w1v + zv.z*w2v + zv.w*w3v;
    }
  }
  int cidx = e*16 + (j0>>8);
#pragma unroll
  for (int bb=0;bb<16;bb++)
    partial[((size_t)cidx*16 + bb)*1024 + d0 + tid] = acc[bb];
}

// ---------------- K4b: sum partials, +bias, /S, head GEMV --------------------
__global__ __launch_bounds__(256) void k4b_head(const float* __restrict__ partial,
    const float* __restrict__ gateSum, const float* __restrict__ b2,
    const float* __restrict__ Wh, const float* __restrict__ bh,
    float* __restrict__ out){
  __shared__ float plf[1024];
  int tid = threadIdx.x, bb = blockIdx.x;
  float gs0 = gateSum[0*16+bb], gs1 = gateSum[1*16+bb];
  float gs2 = gateSum[2*16+bb], gs3 = gateSum[3*16+bb];
  for (int d=tid; d<1024; d+=256){
    float s = 0.f;
    for (int c=0;c<64;c++) s += partial[((size_t)c*16 + bb)*1024 + d];
    s += gs0*b2[0*D_+d] + gs1*b2[1*D_+d] + gs2*b2[2*D_+d] + gs3*b2[3*D_+d];
    plf[d] = s * (1.0f/2048.0f);
  }
  __syncthreads();
  if (tid < 250){
    float4 acc = ((const float4*)bh)[tid];
    const float4* whp = (const float4*)Wh + tid;
#pragma unroll 8
    for (int d=0; d<1024; ++d){
      float pv = plf[d];
      float4 wv = whp[(size_t)d*250];
      acc.x += pv*wv.x; acc.y += pv*wv.y; acc.z += pv*wv.z; acc.w += pv*wv.w;
    }
    ((float4*)(out + (size_t)bb*C_))[tid] = acc;
  }
}

extern "C" void kernel_launch(void* const* d_in, const int* in_sizes, int n_in,
                              void* d_out, int out_size, void* d_ws, size_t ws_size,
                              hipStream_t stream){
  (void)in_sizes; (void)n_in; (void)out_size; (void)ws_size;
  const float* x  = (const float*)d_in[0];
  const float* Wg = (const float*)d_in[1];
  const float* bg = (const float*)d_in[2];
  const float* W1 = (const float*)d_in[3];
  const float* b1 = (const float*)d_in[4];
  const float* W2 = (const float*)d_in[5];
  const float* b2 = (const float*)d_in[6];
  const float* Wh = (const float*)d_in[7];
  const float* bh = (const float*)d_in[8];
  float* out = (float*)d_out;
  char* ws = (char*)d_ws;

  float*    probSum  = (float*)(ws + 0);         // 16B
  unsigned* cntBE    = (unsigned*)(ws + 64);     // 256B (g = e*16+b)
  float*    gateSum  = (float*)(ws + 320);       // 256B
  unsigned* groupOff = (unsigned*)(ws + 576);    // 260B
  int*      expertOff= (int*)(ws + 840);         // 20B
  int*      tileTab  = (int*)(ws + 864);         // 544B (136 ints)
  unsigned* cursor   = (unsigned*)(ws + 2048);   // 8KB (stride-32)
  float*    z        = (float*)(ws + 16384);     // 1MB  -> 1064960
  float4*   logits4  = (float4*)(ws + 1064960);  // 512KB -> 1589248
  unsigned short* xbf = (unsigned short*)(ws + 1593344);  // 64MB -> 68702208
  float*    partial  = (float*)(ws + 1593344);   // 4MB, overlaps xbf (live k4a->k4b)
  int*      perm     = (int*)(ws + 68702208);    // 128KB
  float*    gate     = (float*)(ws + 68833280);  // 128KB
  int*      eidx     = (int*)(ws + 68964352);    // 128KB
  float*    gateP    = (float*)(ws + 69095424);  // 128KB
  unsigned short* w1t = (unsigned short*)(ws + 69226496); // 32MB -> 102780928

  hipMemsetAsync(ws, 0, 1064960, stream);   // counters + tables + z
  k0_transpose<<<dim3(64,16,4), 256, 0, stream>>>(W1, w1t);
  k1_gate<<<512, 256, 0, stream>>>(x, Wg, xbf, logits4);
  k1b_route<<<128, 256, 0, stream>>>(logits4, bg, gate, eidx, probSum, cntBE, gateSum);
  k2a_offsets<<<1, 64, 0, stream>>>(cntBE, probSum, groupOff, cursor, expertOff, tileTab, out + 16000);
  k2b_scatter<<<128, 256, 0, stream>>>(eidx, gate, cursor, perm, gateP);
  k3_moe<<<2112, 512, 0, stream>>>(xbf, w1t, b1, gateP, perm, expertOff, tileTab, z);
  k4a_down<<<dim3(4,16,4), 256, 0, stream>>>(z, W2, partial);
  k4b_head<<<16, 256, 0, stream>>>(partial, gateSum, b2, Wh, bh, out);
}